// Round 14
// baseline (468.825 us; speedup 1.0000x reference)
//
#include <hip/hip_runtime.h>
#include <hip/hip_fp16.h>

#define BNEPS 1e-5f

// ---------------- utility ----------------

__global__ void k_fill(float* p, int n, float v){
  int i = blockIdx.x*blockDim.x + threadIdx.x;
  if(i < n) p[i] = v;
}

// ---------------- CSR build (counting sort by dst; R11 measured-best form) ----------------
// k_count records each edge's arrival rank -> scatter needs NO atomics.

__global__ void k_count(int* cnt, int* rank, const int* __restrict__ dst, int E){
  int e = blockIdx.x*blockDim.x + threadIdx.x;
  if(e < E) rank[e] = atomicAdd(&cnt[dst[e]], 1);
}

__global__ void k_scan1(const int* __restrict__ cnt, int* rowptr, int* bsum, int n){
  __shared__ int sh[256];
  int tid = threadIdx.x;
  int i = blockIdx.x*256 + tid;
  int v = (i < n) ? cnt[i] : 0;
  sh[tid] = v;
  __syncthreads();
  for(int o = 1; o < 256; o <<= 1){
    int t = (tid >= o) ? sh[tid-o] : 0;
    __syncthreads();
    sh[tid] += t;
    __syncthreads();
  }
  if(i < n) rowptr[i] = sh[tid] - v;
  if(tid == 255) bsum[blockIdx.x] = sh[255];
}

__global__ void k_scan2(int* bsum, int m){
  __shared__ int sh[256];
  int tid = threadIdx.x;
  int v = (tid < m) ? bsum[tid] : 0;
  sh[tid] = v;
  __syncthreads();
  for(int o = 1; o < 256; o <<= 1){
    int t = (tid >= o) ? sh[tid-o] : 0;
    __syncthreads();
    sh[tid] += t;
    __syncthreads();
  }
  if(tid < m) bsum[tid] = sh[tid] - v;
}

__global__ void k_scan3(int* rowptr, const int* bsum, int n, int E){
  int i = blockIdx.x*blockDim.x + threadIdx.x;
  if(i < n) rowptr[i] += bsum[i >> 8];
  if(i == 0) rowptr[n] = E;
}

// atomic-free scatter: final position known from rank
__global__ void k_scatter2(const int* __restrict__ src, const int* __restrict__ dst,
                           const float* __restrict__ w, const int* __restrict__ rowptr,
                           const int* __restrict__ rank, int2* __restrict__ erec, int E){
  int e = blockIdx.x*blockDim.x + threadIdx.x;
  if(e >= E) return;
  int d = dst[e];
  erec[rowptr[d] + rank[e]] = make_int2(src[e], __float_as_int(w[e]));
}

__global__ void k_degdis(const int2* __restrict__ erec, const int* __restrict__ rowptr,
                         float* __restrict__ dis, int n){
  int i = blockIdx.x*blockDim.x + threadIdx.x;
  if(i >= n) return;
  float s = 1.0f;                       // self-loop weight
  int e0 = rowptr[i], e1 = rowptr[i+1];
  for(int j = e0; j < e1; j++) s += __int_as_float(erec[j].y);
  dis[i] = rsqrtf(s);
}

__global__ void k_mknorm(int2* __restrict__ erec, const int* __restrict__ rowptr,
                         const float* __restrict__ dis, int n){
  int i = blockIdx.x*blockDim.x + threadIdx.x;
  if(i >= n) return;
  float di = dis[i];
  int e0 = rowptr[i], e1 = rowptr[i+1];
  for(int j = e0; j < e1; j++){
    int2 r = erec[j];
    erec[j].y = __float_as_int(dis[r.x] * __int_as_float(r.y) * di);
  }
}

// ---------------- block1 fused: gather(x)[4ch] + GEMM(4->64) + stats ----------------
// grid 2048 (8 blocks/CU): R12 profile showed 16% occupancy at grid 512 (latency-bound).

__global__ __launch_bounds__(256)
void k_gcn1_fused(const float* __restrict__ X, const float* __restrict__ dis,
                  const int* __restrict__ rowptr, const int2* __restrict__ erec,
                  const float* __restrict__ W, const float* __restrict__ bias,
                  float* __restrict__ H, float* __restrict__ stats, int n){
  const int tid = threadIdx.x;
  const int lane = tid & 63;
  const int wid = tid >> 6;            // 4 waves/block
  const int eg = lane >> 2;            // 16 edge groups
  const int ch = lane & 3;             // input channel
  const float w0 = W[lane], w1 = W[64+lane], w2 = W[128+lane], w3 = W[192+lane];
  const float bc = bias[lane];
  float s = 0.f, s2 = 0.f;
  for(int i = blockIdx.x*4 + wid; i < n; i += gridDim.x*4){
    int e0 = rowptr[i], e1 = rowptr[i+1];
    float acc = 0.f;
    for(int j = e0 + eg; j < e1; j += 16){
      int2 r = erec[j];
      acc += X[(size_t)r.x*4 + ch] * __int_as_float(r.y);
    }
    if(eg == 0){
      float d = dis[i];
      acc += X[(size_t)i*4 + ch] * d * d;
    }
    acc += __shfl_xor(acc, 4);
    acc += __shfl_xor(acc, 8);
    acc += __shfl_xor(acc, 16);
    acc += __shfl_xor(acc, 32);
    float p0 = __shfl(acc, 0), p1 = __shfl(acc, 1);
    float p2 = __shfl(acc, 2), p3 = __shfl(acc, 3);
    float h = bc + p0*w0 + p1*w1 + p2*w2 + p3*w3;
    H[(size_t)i*64 + lane] = h;
    s += h; s2 += h*h;
  }
  __shared__ float rs[256], rs2[256];
  rs[tid] = s; rs2[tid] = s2;
  __syncthreads();
  if(tid < 64){
    atomicAdd(&stats[tid],    rs[tid]+rs[tid+64]+rs[tid+128]+rs[tid+192]);
    atomicAdd(&stats[64+tid], rs2[tid]+rs2[tid+64]+rs2[tid+128]+rs2[tid+192]);
  }
}

// ---------------- 64-channel gather from fp16 activations ----------------
// One wave per node; each edge row read is 128B (half the fp32 traffic).

__global__ void k_gather64h(const __half* __restrict__ H, const float* __restrict__ dis,
                            const int* __restrict__ rowptr, const int2* __restrict__ erec,
                            float* __restrict__ P, int n){
  int i = blockIdx.x*4 + threadIdx.x / 64;
  int c = threadIdx.x & 63;
  if(i >= n) return;
  float di = dis[i];
  float acc = __half2float(H[(size_t)i*64 + c])*di*di;
  int e0 = rowptr[i], e1 = rowptr[i+1];
  int j = e0;
  for(; j + 8 <= e1; j += 8){
    int2 r0 = erec[j],   r1 = erec[j+1], r2 = erec[j+2], r3 = erec[j+3];
    int2 r4 = erec[j+4], r5 = erec[j+5], r6 = erec[j+6], r7 = erec[j+7];
    float h0 = __half2float(H[(size_t)r0.x*64 + c]);
    float h1 = __half2float(H[(size_t)r1.x*64 + c]);
    float h2 = __half2float(H[(size_t)r2.x*64 + c]);
    float h3 = __half2float(H[(size_t)r3.x*64 + c]);
    float h4 = __half2float(H[(size_t)r4.x*64 + c]);
    float h5 = __half2float(H[(size_t)r5.x*64 + c]);
    float h6 = __half2float(H[(size_t)r6.x*64 + c]);
    float h7 = __half2float(H[(size_t)r7.x*64 + c]);
    acc += h0*__int_as_float(r0.y) + h1*__int_as_float(r1.y)
         + h2*__int_as_float(r2.y) + h3*__int_as_float(r3.y)
         + h4*__int_as_float(r4.y) + h5*__int_as_float(r5.y)
         + h6*__int_as_float(r6.y) + h7*__int_as_float(r7.y);
  }
  for(; j < e1; j++){
    int2 r = erec[j];
    acc += __half2float(H[(size_t)r.x*64 + c]) * __int_as_float(r.y);
  }
  P[(size_t)i*64 + c] = acc;
}

// ---------------- register-tiled LDS GEMMs (K=64) ----------------

template<int C>
__global__ __launch_bounds__(256)
void k_gemm_tile(const float* __restrict__ X, const float* __restrict__ W,
                 const float* __restrict__ bias, float* __restrict__ H,
                 float* __restrict__ stats, int n, int ntiles){
  const int RR = C/16;
  const int CG = C/4;
  __shared__ float Xs[64*65];
  __shared__ float Ws[64*C];
  __shared__ float sst[2*C];
  const int tid = threadIdx.x;
  const int cg = tid % CG, rg = tid / CG;
  const int c0 = cg*4;
  for(int t = tid; t < 16*C; t += 256)
    reinterpret_cast<float4*>(Ws)[t] = reinterpret_cast<const float4*>(W)[t];
  const float4 bc = *reinterpret_cast<const float4*>(bias + c0);
  float sacc[4] = {0,0,0,0}, qacc[4] = {0,0,0,0};
  const float4* X4 = reinterpret_cast<const float4*>(X);
  for(int tile = blockIdx.x; tile < ntiles; tile += gridDim.x){
    const int r0 = tile*64;
    __syncthreads();
    #pragma unroll
    for(int q = 0; q < 4; q++){
      int idx = tid + q*256;
      int row = idx >> 4, k4 = idx & 15;
      float4 v = (r0+row < n) ? X4[(size_t)(r0+row)*16 + k4] : make_float4(0.f,0.f,0.f,0.f);
      Xs[(4*k4+0)*65 + row] = v.x;
      Xs[(4*k4+1)*65 + row] = v.y;
      Xs[(4*k4+2)*65 + row] = v.z;
      Xs[(4*k4+3)*65 + row] = v.w;
    }
    __syncthreads();
    float acc[RR][4];
    #pragma unroll
    for(int r = 0; r < RR; r++){ acc[r][0]=bc.x; acc[r][1]=bc.y; acc[r][2]=bc.z; acc[r][3]=bc.w; }
    #pragma unroll 8
    for(int k = 0; k < 64; k++){
      float4 wv = reinterpret_cast<const float4*>(Ws)[k*CG + cg];
      #pragma unroll
      for(int r = 0; r < RR; r++){
        float xv = Xs[k*65 + rg*RR + r];
        acc[r][0] = fmaf(xv, wv.x, acc[r][0]);
        acc[r][1] = fmaf(xv, wv.y, acc[r][1]);
        acc[r][2] = fmaf(xv, wv.z, acc[r][2]);
        acc[r][3] = fmaf(xv, wv.w, acc[r][3]);
      }
    }
    #pragma unroll
    for(int r = 0; r < RR; r++){
      int row = r0 + rg*RR + r;
      if(row < n){
        *reinterpret_cast<float4*>(H + (size_t)row*C + c0) =
            make_float4(acc[r][0], acc[r][1], acc[r][2], acc[r][3]);
        #pragma unroll
        for(int j = 0; j < 4; j++){ sacc[j] += acc[r][j]; qacc[j] += acc[r][j]*acc[r][j]; }
      }
    }
  }
  for(int t = tid; t < 2*C; t += 256) sst[t] = 0.f;
  __syncthreads();
  #pragma unroll
  for(int j = 0; j < 4; j++){
    atomicAdd(&sst[c0+j], sacc[j]);
    atomicAdd(&sst[C+c0+j], qacc[j]);
  }
  __syncthreads();
  for(int t = tid; t < 2*C; t += 256) atomicAdd(&stats[t], sst[t]);
}

// out = relu(bn(agg)) + Xh@sW+sb  — shortcut GEMM from fp16 X + BN epilogue (C=128)
__global__ __launch_bounds__(256)
void k_gemm_bnsc_tile_h(const __half* __restrict__ Xh, const float* __restrict__ sW,
                        const float* __restrict__ sb,
                        const float* __restrict__ agg, const float* __restrict__ stats,
                        const float* __restrict__ g, const float* __restrict__ be,
                        float* __restrict__ out, int n, int ntiles){
  const int C = 128, RR = 8, CG = 32;
  __shared__ float Xs[64*65];
  __shared__ float Ws[64*C];
  const int tid = threadIdx.x;
  const int cg = tid % CG, rg = tid / CG;
  const int c0 = cg*4;
  for(int t = tid; t < 16*C; t += 256)
    reinterpret_cast<float4*>(Ws)[t] = reinterpret_cast<const float4*>(sW)[t];
  const float4 bc = *reinterpret_cast<const float4*>(sb + c0);
  float scal[4], shft[4];
  {
    float invn = 1.0f / n;
    #pragma unroll
    for(int j = 0; j < 4; j++){
      float m = stats[c0+j]*invn;
      float v = stats[C+c0+j]*invn - m*m;
      float rs = rsqrtf(v + BNEPS) * g[c0+j];
      scal[j] = rs;
      shft[j] = be[c0+j] - m*rs;
    }
  }
  for(int tile = blockIdx.x; tile < ntiles; tile += gridDim.x){
    const int r0 = tile*64;
    __syncthreads();
    // stage 64 rows x 64 halves: 8 chunks of 8 halves per row (16B loads)
    #pragma unroll
    for(int q = 0; q < 2; q++){
      int t = tid + q*256;                 // 512 chunks
      int row = t >> 3, h8 = t & 7;
      float4 raw = make_float4(0.f,0.f,0.f,0.f);
      if(r0+row < n) raw = *reinterpret_cast<const float4*>(Xh + (size_t)(r0+row)*64 + h8*8);
      const __half2* hp = reinterpret_cast<const __half2*>(&raw);
      #pragma unroll
      for(int p = 0; p < 4; p++){
        float2 f = __half22float2(hp[p]);
        Xs[(h8*8 + 2*p    )*65 + row] = f.x;
        Xs[(h8*8 + 2*p + 1)*65 + row] = f.y;
      }
    }
    __syncthreads();
    float acc[RR][4];
    #pragma unroll
    for(int r = 0; r < RR; r++){ acc[r][0]=bc.x; acc[r][1]=bc.y; acc[r][2]=bc.z; acc[r][3]=bc.w; }
    #pragma unroll 8
    for(int k = 0; k < 64; k++){
      float4 wv = reinterpret_cast<const float4*>(Ws)[k*CG + cg];
      #pragma unroll
      for(int r = 0; r < RR; r++){
        float xv = Xs[k*65 + rg*RR + r];
        acc[r][0] = fmaf(xv, wv.x, acc[r][0]);
        acc[r][1] = fmaf(xv, wv.y, acc[r][1]);
        acc[r][2] = fmaf(xv, wv.z, acc[r][2]);
        acc[r][3] = fmaf(xv, wv.w, acc[r][3]);
      }
    }
    #pragma unroll
    for(int r = 0; r < RR; r++){
      int row = r0 + rg*RR + r;
      if(row < n){
        float4 a = *reinterpret_cast<const float4*>(agg + (size_t)row*C + c0);
        float4 o;
        o.x = fmaxf(a.x*scal[0] + shft[0], 0.f) + acc[r][0];
        o.y = fmaxf(a.y*scal[1] + shft[1], 0.f) + acc[r][1];
        o.z = fmaxf(a.z*scal[2] + shft[2], 0.f) + acc[r][2];
        o.w = fmaxf(a.w*scal[3] + shft[3], 0.f) + acc[r][3];
        *reinterpret_cast<float4*>(out + (size_t)row*C + c0) = o;
      }
    }
  }
}

// ---------------- BN applies (fp16 activation output) ----------------

// block2 epilogue: bufA = half( relu(bn(agg)) + bufA_old )   (C=64, in place)
__global__ void k_bn_add4_h(const float* __restrict__ agg, const float* __restrict__ stats,
                            const float* __restrict__ g, const float* __restrict__ be,
                            __half* __restrict__ buf, int n){
  int idx = blockIdx.x*blockDim.x + threadIdx.x;    // over n*16
  if(idx >= n*16) return;
  int c = (idx & 15)*4;
  float invn = 1.0f / n;
  float4 sm = *reinterpret_cast<const float4*>(stats + c);
  float4 sq = *reinterpret_cast<const float4*>(stats + 64 + c);
  float4 g4 = *reinterpret_cast<const float4*>(g + c);
  float4 b4 = *reinterpret_cast<const float4*>(be + c);
  float4 a  = reinterpret_cast<const float4*>(agg)[idx];
  __half2* bp = reinterpret_cast<__half2*>(buf) + idx*2;
  float2 ad01 = __half22float2(bp[0]);
  float2 ad23 = __half22float2(bp[1]);
  float o0,o1,o2,o3;
  { float m=sm.x*invn, v=sq.x*invn-m*m; o0 = fmaxf((a.x-m)*rsqrtf(v+BNEPS)*g4.x+b4.x,0.f)+ad01.x; }
  { float m=sm.y*invn, v=sq.y*invn-m*m; o1 = fmaxf((a.y-m)*rsqrtf(v+BNEPS)*g4.y+b4.y,0.f)+ad01.y; }
  { float m=sm.z*invn, v=sq.z*invn-m*m; o2 = fmaxf((a.z-m)*rsqrtf(v+BNEPS)*g4.z+b4.z,0.f)+ad23.x; }
  { float m=sm.w*invn, v=sq.w*invn-m*m; o3 = fmaxf((a.w-m)*rsqrtf(v+BNEPS)*g4.w+b4.w,0.f)+ad23.y; }
  bp[0] = __floats2half2_rn(o0,o1);
  bp[1] = __floats2half2_rn(o2,o3);
}

// block1 epilogue: bufA = half( relu(bn(agg)) + x@sW + sb )   (C=64)
__global__ void k_bn_sc4_h(const float* __restrict__ agg, const float* __restrict__ stats,
                           const float* __restrict__ g, const float* __restrict__ be,
                           const float* __restrict__ X, const float* __restrict__ sW,
                           const float* __restrict__ sb, __half* __restrict__ out, int n){
  int idx = blockIdx.x*blockDim.x + threadIdx.x;    // over n*16
  if(idx >= n*16) return;
  int i = idx >> 4;
  int c = (idx & 15)*4;
  float invn = 1.0f / n;
  float4 xr = *reinterpret_cast<const float4*>(X + (size_t)i*4);
  float4 s0 = *reinterpret_cast<const float4*>(sW + c);
  float4 s1 = *reinterpret_cast<const float4*>(sW + 64 + c);
  float4 s2 = *reinterpret_cast<const float4*>(sW + 128 + c);
  float4 s3 = *reinterpret_cast<const float4*>(sW + 192 + c);
  float4 sb4 = *reinterpret_cast<const float4*>(sb + c);
  float4 sm = *reinterpret_cast<const float4*>(stats + c);
  float4 sq = *reinterpret_cast<const float4*>(stats + 64 + c);
  float4 g4 = *reinterpret_cast<const float4*>(g + c);
  float4 b4 = *reinterpret_cast<const float4*>(be + c);
  float4 a  = reinterpret_cast<const float4*>(agg)[idx];
  float o0,o1,o2,o3;
  #define BN1(X_, O_) { float sc = xr.x*s0.X_ + xr.y*s1.X_ + xr.z*s2.X_ + xr.w*s3.X_ + sb4.X_; \
    float m = sm.X_*invn; float v = sq.X_*invn - m*m; \
    O_ = fmaxf((a.X_-m)*rsqrtf(v+BNEPS)*g4.X_ + b4.X_, 0.f) + sc; }
  BN1(x,o0) BN1(y,o1) BN1(z,o2) BN1(w,o3)
  #undef BN1
  __half2* op = reinterpret_cast<__half2*>(out) + idx*2;
  op[0] = __floats2half2_rn(o0,o1);
  op[1] = __floats2half2_rn(o2,o3);
}

// ---------------- pooling / head ----------------

__global__ void k_pool(const float* __restrict__ H, const int* __restrict__ batch,
                       float* __restrict__ z, int n){
  int b = blockIdx.x, c = threadIdx.x;
  int lo = 0, hi = n;
  while(lo < hi){ int mid = (lo+hi)>>1; if(batch[mid] <  b) lo = mid+1; else hi = mid; }
  int start = lo;
  hi = n;
  while(lo < hi){ int mid = (lo+hi)>>1; if(batch[mid] <  b+1) lo = mid+1; else hi = mid; }
  int end = lo;
  float s = 0.f, mx = -INFINITY;
  for(int i = start; i < end; i++){
    float v = H[(size_t)i*128 + c];
    s += v; mx = fmaxf(mx, v);
  }
  int cnt = end - start;
  z[b*256 + c]       = s / fmaxf((float)cnt, 1.f);
  z[b*256 + 128 + c] = mx;
}

__global__ void k_head1(const float* __restrict__ z, const float* __restrict__ fW1,
                        const float* __restrict__ fb1, float* __restrict__ zr,
                        float* __restrict__ stats, int B){
  int idx = blockIdx.x*blockDim.x + threadIdx.x;
  int tid = threadIdx.x;
  float acc = 0.f;
  if(idx < B*128){
    int b = idx >> 7, c = idx & 127;
    acc = fb1[c];
    #pragma unroll 4
    for(int k = 0; k < 256; k++) acc = fmaf(z[b*256+k], fW1[k*128+c], acc);
    zr[idx] = acc;
  }
  __shared__ float rs[256], rs2[256];
  rs[tid] = acc; rs2[tid] = acc*acc;
  __syncthreads();
  if(tid < 128){
    atomicAdd(&stats[tid],     rs[tid]+rs[tid+128]);
    atomicAdd(&stats[128+tid], rs2[tid]+rs2[tid+128]);
  }
}

__global__ void k_final(const float* __restrict__ zr, const float* __restrict__ stats,
                        const float* __restrict__ fg, const float* __restrict__ fbe,
                        const float* __restrict__ fW2, const float* __restrict__ fb2,
                        float* __restrict__ out, int B){
  __shared__ float red[128];
  int b = blockIdx.x, c = threadIdx.x;
  float invn = 1.0f / B;
  float m  = stats[c]*invn;
  float v  = stats[128+c]*invn - m*m;
  float rs = rsqrtf(v + BNEPS);
  float val = fmaxf((zr[b*128+c]-m)*rs*fg[c] + fbe[c], 0.f) * fW2[c];
  red[c] = val;
  __syncthreads();
  for(int s = 64; s > 0; s >>= 1){
    if(c < s) red[c] += red[c+s];
    __syncthreads();
  }
  if(c == 0) out[b] = red[0] + fb2[0];
}

// ---------------- launch ----------------

extern "C" void kernel_launch(void* const* d_in, const int* in_sizes, int n_in,
                              void* d_out, int out_size, void* d_ws, size_t ws_size,
                              hipStream_t stream){
  const float* x   = (const float*)d_in[0];
  const int*   ei  = (const int*)  d_in[1];
  const float* ew  = (const float*)d_in[2];
  const int*   bat = (const int*)  d_in[3];
  const float* W1  = (const float*)d_in[4];  const float* b1  = (const float*)d_in[5];
  const float* g1  = (const float*)d_in[6];  const float* be1 = (const float*)d_in[7];
  const float* sW1 = (const float*)d_in[8];  const float* sb1 = (const float*)d_in[9];
  const float* W2  = (const float*)d_in[10]; const float* b2  = (const float*)d_in[11];
  const float* g2  = (const float*)d_in[12]; const float* be2 = (const float*)d_in[13];
  const float* W3  = (const float*)d_in[14]; const float* b3  = (const float*)d_in[15];
  const float* g3  = (const float*)d_in[16]; const float* be3 = (const float*)d_in[17];
  const float* sW3 = (const float*)d_in[18]; const float* sb3 = (const float*)d_in[19];
  const float* fW1 = (const float*)d_in[20]; const float* fb1 = (const float*)d_in[21];
  const float* fg  = (const float*)d_in[22]; const float* fbe = (const float*)d_in[23];
  const float* fW2 = (const float*)d_in[24]; const float* fb2 = (const float*)d_in[25];
  float* out = (float*)d_out;

  const int n = in_sizes[0] / 4;
  const int E = in_sizes[2];
  const int B = out_size;          // 512
  const int* src = ei;
  const int* dst = ei + E;

  auto GB = [](long long t){ return (int)((t + 255) / 256); };
  const int nscanb = (n + 255) / 256;   // <= 256 required for k_scan2
  const int ntiles = (n + 63) / 64;

  float* ws = (float*)d_ws;
  size_t off = 0;
  auto alloc = [&](size_t cnt)->float*{ float* p = ws + off; off += (cnt + 63) & ~size_t(63); return p; };

  const size_t npad = ((size_t)n + 63) & ~size_t(63);
  __half* bufA = (__half*)alloc((size_t)n * 32);   // n*64 halves
  float* hbuf  = alloc((size_t)n * 128);           // P buffers / block3 output
  float* agg   = alloc((size_t)n * 128);
  float* z     = alloc((size_t)B * 256);
  float* zr    = alloc((size_t)B * 128);
  float* zreg  = alloc(npad + 1024);               // cnt(n ints) + 4x256 stats
  int*   cnt   = (int*)zreg;
  float* st1 = zreg + npad; float* st2 = st1 + 256;
  float* st3 = st2 + 256;   float* stH = st3 + 256;
  float* dis    = alloc(n);
  int*   rowptr = (int*)alloc(n + 1);
  int*   bsum   = (int*)alloc(256);
  int*   rank   = (int*)alloc(E);
  int2*  erec   = (int2*)alloc((size_t)E * 2);

  // ---- CSR build: count records per-edge rank -> atomic-free scatter
  k_fill<<<GB(npad + 1024),256,0,stream>>>(zreg, (int)(npad + 1024), 0.f);
  k_count<<<GB(E),256,0,stream>>>(cnt, rank, dst, E);
  k_scan1<<<nscanb,256,0,stream>>>(cnt, rowptr, bsum, n);
  k_scan2<<<1,256,0,stream>>>(bsum, nscanb);
  k_scan3<<<GB(n),256,0,stream>>>(rowptr, bsum, n, E);
  k_scatter2<<<GB(E),256,0,stream>>>(src, dst, ew, rowptr, rank, erec, E);
  k_degdis<<<GB(n),256,0,stream>>>(erec, rowptr, dis, n);
  k_mknorm<<<GB(n),256,0,stream>>>(erec, rowptr, dis, n);

  // ---- block1: fused gather(x,4ch)+GEMM(4->64)+stats -> agg; BN+ReLU+shortcut -> bufA(h)
  float* P = hbuf;
  k_gcn1_fused<<<2048,256,0,stream>>>(x, dis, rowptr, erec, W1, b1, agg, st1, n);
  k_bn_sc4_h<<<GB((long long)n*16),256,0,stream>>>(agg, st1, g1, be1, x, sW1, sb1, bufA, n);

  // ---- block2: P=gather(bufA h); agg=P@W2+b2 (+stats); BN+ReLU+identity -> bufA(h)
  k_gather64h<<<(n+3)/4,256,0,stream>>>(bufA, dis, rowptr, erec, P, n);
  k_gemm_tile<64><<<512,256,0,stream>>>(P, W2, b2, agg, st2, n, ntiles);
  k_bn_add4_h<<<GB((long long)n*16),256,0,stream>>>(agg, st2, g2, be2, bufA, n);

  // ---- block3: P=gather(bufA h); agg=P@W3+b3 (+stats); fused shortcut(h)+BN -> hbuf
  k_gather64h<<<(n+3)/4,256,0,stream>>>(bufA, dis, rowptr, erec, P, n);
  k_gemm_tile<128><<<512,256,0,stream>>>(P, W3, b3, agg, st3, n, ntiles);
  k_gemm_bnsc_tile_h<<<512,256,0,stream>>>(bufA, sW3, sb3, agg, st3, g3, be3, hbuf, n, ntiles);

  // ---- pooling + head ----
  k_pool<<<B,128,0,stream>>>(hbuf, bat, z, n);
  k_head1<<<GB((long long)B*128),256,0,stream>>>(z, fW1, fb1, zr, stH, B);
  k_final<<<B,128,0,stream>>>(zr, stH, fg, fbe, fW2, fb2, out, B);
}

// Round 15
// 429.711 us; speedup vs baseline: 1.0910x; 1.0910x over previous
//
#include <hip/hip_runtime.h>
#include <hip/hip_fp16.h>

#define BNEPS 1e-5f

// ---------------- utility ----------------

__global__ void k_fill(float* p, int n, float v){
  int i = blockIdx.x*blockDim.x + threadIdx.x;
  if(i < n) p[i] = v;
}

// ---------------- CSR build (counting sort by dst; R11 measured-best form) ----------------

__global__ void k_count(int* cnt, int* rank, const int* __restrict__ dst, int E){
  int e = blockIdx.x*blockDim.x + threadIdx.x;
  if(e < E) rank[e] = atomicAdd(&cnt[dst[e]], 1);
}

__global__ void k_scan1(const int* __restrict__ cnt, int* rowptr, int* bsum, int n){
  __shared__ int sh[256];
  int tid = threadIdx.x;
  int i = blockIdx.x*256 + tid;
  int v = (i < n) ? cnt[i] : 0;
  sh[tid] = v;
  __syncthreads();
  for(int o = 1; o < 256; o <<= 1){
    int t = (tid >= o) ? sh[tid-o] : 0;
    __syncthreads();
    sh[tid] += t;
    __syncthreads();
  }
  if(i < n) rowptr[i] = sh[tid] - v;
  if(tid == 255) bsum[blockIdx.x] = sh[255];
}

__global__ void k_scan2(int* bsum, int m){
  __shared__ int sh[256];
  int tid = threadIdx.x;
  int v = (tid < m) ? bsum[tid] : 0;
  sh[tid] = v;
  __syncthreads();
  for(int o = 1; o < 256; o <<= 1){
    int t = (tid >= o) ? sh[tid-o] : 0;
    __syncthreads();
    sh[tid] += t;
    __syncthreads();
  }
  if(tid < m) bsum[tid] = sh[tid] - v;
}

__global__ void k_scan3(int* rowptr, const int* bsum, int n, int E){
  int i = blockIdx.x*blockDim.x + threadIdx.x;
  if(i < n) rowptr[i] += bsum[i >> 8];
  if(i == 0) rowptr[n] = E;
}

__global__ void k_scatter2(const int* __restrict__ src, const int* __restrict__ dst,
                           const float* __restrict__ w, const int* __restrict__ rowptr,
                           const int* __restrict__ rank, int2* __restrict__ erec, int E){
  int e = blockIdx.x*blockDim.x + threadIdx.x;
  if(e >= E) return;
  int d = dst[e];
  erec[rowptr[d] + rank[e]] = make_int2(src[e], __float_as_int(w[e]));
}

__global__ void k_degdis(const int2* __restrict__ erec, const int* __restrict__ rowptr,
                         float* __restrict__ dis, int n){
  int i = blockIdx.x*blockDim.x + threadIdx.x;
  if(i >= n) return;
  float s = 1.0f;                       // self-loop weight
  int e0 = rowptr[i], e1 = rowptr[i+1];
  for(int j = e0; j < e1; j++) s += __int_as_float(erec[j].y);
  dis[i] = rsqrtf(s);
}

__global__ void k_mknorm(int2* __restrict__ erec, const int* __restrict__ rowptr,
                         const float* __restrict__ dis, int n){
  int i = blockIdx.x*blockDim.x + threadIdx.x;
  if(i >= n) return;
  float di = dis[i];
  int e0 = rowptr[i], e1 = rowptr[i+1];
  for(int j = e0; j < e1; j++){
    int2 r = erec[j];
    erec[j].y = __float_as_int(dis[r.x] * __int_as_float(r.y) * di);
  }
}

// ---------------- block1 fused: gather(x)[4ch] + GEMM(4->64) + SHARDED stats ----------------
// grid 2048 for latency hiding; stats sharded 8x (st1s[blockIdx&7][128]) so
// per-address atomic serialization is 256 not 2048 (R13 lesson: epilogue
// atomics scale with gridDim; R10 lesson: contention ~ adds/address).

__global__ __launch_bounds__(256)
void k_gcn1_fused(const float* __restrict__ X, const float* __restrict__ dis,
                  const int* __restrict__ rowptr, const int2* __restrict__ erec,
                  const float* __restrict__ W, const float* __restrict__ bias,
                  float* __restrict__ H, float* __restrict__ st1s, int n){
  const int tid = threadIdx.x;
  const int lane = tid & 63;
  const int wid = tid >> 6;            // 4 waves/block
  const int eg = lane >> 2;            // 16 edge groups
  const int ch = lane & 3;             // input channel
  const float w0 = W[lane], w1 = W[64+lane], w2 = W[128+lane], w3 = W[192+lane];
  const float bc = bias[lane];
  float s = 0.f, s2 = 0.f;
  for(int i = blockIdx.x*4 + wid; i < n; i += gridDim.x*4){
    int e0 = rowptr[i], e1 = rowptr[i+1];
    float acc = 0.f;
    for(int j = e0 + eg; j < e1; j += 16){
      int2 r = erec[j];
      acc += X[(size_t)r.x*4 + ch] * __int_as_float(r.y);
    }
    if(eg == 0){
      float d = dis[i];
      acc += X[(size_t)i*4 + ch] * d * d;
    }
    acc += __shfl_xor(acc, 4);
    acc += __shfl_xor(acc, 8);
    acc += __shfl_xor(acc, 16);
    acc += __shfl_xor(acc, 32);
    float p0 = __shfl(acc, 0), p1 = __shfl(acc, 1);
    float p2 = __shfl(acc, 2), p3 = __shfl(acc, 3);
    float h = bc + p0*w0 + p1*w1 + p2*w2 + p3*w3;
    H[(size_t)i*64 + lane] = h;
    s += h; s2 += h*h;
  }
  __shared__ float rs[256], rs2[256];
  rs[tid] = s; rs2[tid] = s2;
  __syncthreads();
  if(tid < 64){
    float* stp = st1s + (blockIdx.x & 7)*128;
    atomicAdd(&stp[tid],    rs[tid]+rs[tid+64]+rs[tid+128]+rs[tid+192]);
    atomicAdd(&stp[64+tid], rs2[tid]+rs2[tid+64]+rs2[tid+128]+rs2[tid+192]);
  }
}

// ---------------- 64-channel gather from fp16 activations ----------------

__global__ void k_gather64h(const __half* __restrict__ H, const float* __restrict__ dis,
                            const int* __restrict__ rowptr, const int2* __restrict__ erec,
                            float* __restrict__ P, int n){
  int i = blockIdx.x*4 + threadIdx.x / 64;
  int c = threadIdx.x & 63;
  if(i >= n) return;
  float di = dis[i];
  float acc = __half2float(H[(size_t)i*64 + c])*di*di;
  int e0 = rowptr[i], e1 = rowptr[i+1];
  int j = e0;
  for(; j + 8 <= e1; j += 8){
    int2 r0 = erec[j],   r1 = erec[j+1], r2 = erec[j+2], r3 = erec[j+3];
    int2 r4 = erec[j+4], r5 = erec[j+5], r6 = erec[j+6], r7 = erec[j+7];
    float h0 = __half2float(H[(size_t)r0.x*64 + c]);
    float h1 = __half2float(H[(size_t)r1.x*64 + c]);
    float h2 = __half2float(H[(size_t)r2.x*64 + c]);
    float h3 = __half2float(H[(size_t)r3.x*64 + c]);
    float h4 = __half2float(H[(size_t)r4.x*64 + c]);
    float h5 = __half2float(H[(size_t)r5.x*64 + c]);
    float h6 = __half2float(H[(size_t)r6.x*64 + c]);
    float h7 = __half2float(H[(size_t)r7.x*64 + c]);
    acc += h0*__int_as_float(r0.y) + h1*__int_as_float(r1.y)
         + h2*__int_as_float(r2.y) + h3*__int_as_float(r3.y)
         + h4*__int_as_float(r4.y) + h5*__int_as_float(r5.y)
         + h6*__int_as_float(r6.y) + h7*__int_as_float(r7.y);
  }
  for(; j < e1; j++){
    int2 r = erec[j];
    acc += __half2float(H[(size_t)r.x*64 + c]) * __int_as_float(r.y);
  }
  P[(size_t)i*64 + c] = acc;
}

// ---------------- register-tiled LDS GEMMs (K=64) ----------------

template<int C>
__global__ __launch_bounds__(256)
void k_gemm_tile(const float* __restrict__ X, const float* __restrict__ W,
                 const float* __restrict__ bias, float* __restrict__ H,
                 float* __restrict__ stats, int n, int ntiles){
  const int RR = C/16;
  const int CG = C/4;
  __shared__ float Xs[64*65];
  __shared__ float Ws[64*C];
  __shared__ float sst[2*C];
  const int tid = threadIdx.x;
  const int cg = tid % CG, rg = tid / CG;
  const int c0 = cg*4;
  for(int t = tid; t < 16*C; t += 256)
    reinterpret_cast<float4*>(Ws)[t] = reinterpret_cast<const float4*>(W)[t];
  const float4 bc = *reinterpret_cast<const float4*>(bias + c0);
  float sacc[4] = {0,0,0,0}, qacc[4] = {0,0,0,0};
  const float4* X4 = reinterpret_cast<const float4*>(X);
  for(int tile = blockIdx.x; tile < ntiles; tile += gridDim.x){
    const int r0 = tile*64;
    __syncthreads();
    #pragma unroll
    for(int q = 0; q < 4; q++){
      int idx = tid + q*256;
      int row = idx >> 4, k4 = idx & 15;
      float4 v = (r0+row < n) ? X4[(size_t)(r0+row)*16 + k4] : make_float4(0.f,0.f,0.f,0.f);
      Xs[(4*k4+0)*65 + row] = v.x;
      Xs[(4*k4+1)*65 + row] = v.y;
      Xs[(4*k4+2)*65 + row] = v.z;
      Xs[(4*k4+3)*65 + row] = v.w;
    }
    __syncthreads();
    float acc[RR][4];
    #pragma unroll
    for(int r = 0; r < RR; r++){ acc[r][0]=bc.x; acc[r][1]=bc.y; acc[r][2]=bc.z; acc[r][3]=bc.w; }
    #pragma unroll 8
    for(int k = 0; k < 64; k++){
      float4 wv = reinterpret_cast<const float4*>(Ws)[k*CG + cg];
      #pragma unroll
      for(int r = 0; r < RR; r++){
        float xv = Xs[k*65 + rg*RR + r];
        acc[r][0] = fmaf(xv, wv.x, acc[r][0]);
        acc[r][1] = fmaf(xv, wv.y, acc[r][1]);
        acc[r][2] = fmaf(xv, wv.z, acc[r][2]);
        acc[r][3] = fmaf(xv, wv.w, acc[r][3]);
      }
    }
    #pragma unroll
    for(int r = 0; r < RR; r++){
      int row = r0 + rg*RR + r;
      if(row < n){
        *reinterpret_cast<float4*>(H + (size_t)row*C + c0) =
            make_float4(acc[r][0], acc[r][1], acc[r][2], acc[r][3]);
        #pragma unroll
        for(int j = 0; j < 4; j++){ sacc[j] += acc[r][j]; qacc[j] += acc[r][j]*acc[r][j]; }
      }
    }
  }
  for(int t = tid; t < 2*C; t += 256) sst[t] = 0.f;
  __syncthreads();
  #pragma unroll
  for(int j = 0; j < 4; j++){
    atomicAdd(&sst[c0+j], sacc[j]);
    atomicAdd(&sst[C+c0+j], qacc[j]);
  }
  __syncthreads();
  for(int t = tid; t < 2*C; t += 256) atomicAdd(&stats[t], sst[t]);
}

// out = relu(bn(agg)) + Xh@sW+sb  — shortcut GEMM from fp16 X + BN epilogue (C=128)
__global__ __launch_bounds__(256)
void k_gemm_bnsc_tile_h(const __half* __restrict__ Xh, const float* __restrict__ sW,
                        const float* __restrict__ sb,
                        const float* __restrict__ agg, const float* __restrict__ stats,
                        const float* __restrict__ g, const float* __restrict__ be,
                        float* __restrict__ out, int n, int ntiles){
  const int C = 128, RR = 8, CG = 32;
  __shared__ float Xs[64*65];
  __shared__ float Ws[64*C];
  const int tid = threadIdx.x;
  const int cg = tid % CG, rg = tid / CG;
  const int c0 = cg*4;
  for(int t = tid; t < 16*C; t += 256)
    reinterpret_cast<float4*>(Ws)[t] = reinterpret_cast<const float4*>(sW)[t];
  const float4 bc = *reinterpret_cast<const float4*>(sb + c0);
  float scal[4], shft[4];
  {
    float invn = 1.0f / n;
    #pragma unroll
    for(int j = 0; j < 4; j++){
      float m = stats[c0+j]*invn;
      float v = stats[C+c0+j]*invn - m*m;
      float rs = rsqrtf(v + BNEPS) * g[c0+j];
      scal[j] = rs;
      shft[j] = be[c0+j] - m*rs;
    }
  }
  for(int tile = blockIdx.x; tile < ntiles; tile += gridDim.x){
    const int r0 = tile*64;
    __syncthreads();
    #pragma unroll
    for(int q = 0; q < 2; q++){
      int t = tid + q*256;                 // 512 chunks of 8 halves
      int row = t >> 3, h8 = t & 7;
      float4 raw = make_float4(0.f,0.f,0.f,0.f);
      if(r0+row < n) raw = *reinterpret_cast<const float4*>(Xh + (size_t)(r0+row)*64 + h8*8);
      const __half2* hp = reinterpret_cast<const __half2*>(&raw);
      #pragma unroll
      for(int p = 0; p < 4; p++){
        float2 f = __half22float2(hp[p]);
        Xs[(h8*8 + 2*p    )*65 + row] = f.x;
        Xs[(h8*8 + 2*p + 1)*65 + row] = f.y;
      }
    }
    __syncthreads();
    float acc[RR][4];
    #pragma unroll
    for(int r = 0; r < RR; r++){ acc[r][0]=bc.x; acc[r][1]=bc.y; acc[r][2]=bc.z; acc[r][3]=bc.w; }
    #pragma unroll 8
    for(int k = 0; k < 64; k++){
      float4 wv = reinterpret_cast<const float4*>(Ws)[k*CG + cg];
      #pragma unroll
      for(int r = 0; r < RR; r++){
        float xv = Xs[k*65 + rg*RR + r];
        acc[r][0] = fmaf(xv, wv.x, acc[r][0]);
        acc[r][1] = fmaf(xv, wv.y, acc[r][1]);
        acc[r][2] = fmaf(xv, wv.z, acc[r][2]);
        acc[r][3] = fmaf(xv, wv.w, acc[r][3]);
      }
    }
    #pragma unroll
    for(int r = 0; r < RR; r++){
      int row = r0 + rg*RR + r;
      if(row < n){
        float4 a = *reinterpret_cast<const float4*>(agg + (size_t)row*C + c0);
        float4 o;
        o.x = fmaxf(a.x*scal[0] + shft[0], 0.f) + acc[r][0];
        o.y = fmaxf(a.y*scal[1] + shft[1], 0.f) + acc[r][1];
        o.z = fmaxf(a.z*scal[2] + shft[2], 0.f) + acc[r][2];
        o.w = fmaxf(a.w*scal[3] + shft[3], 0.f) + acc[r][3];
        *reinterpret_cast<float4*>(out + (size_t)row*C + c0) = o;
      }
    }
  }
}

// ---------------- BN applies (fp16 activation output) ----------------

// block2 epilogue: bufA = half( relu(bn(agg)) + bufA_old )   (C=64, in place)
__global__ void k_bn_add4_h(const float* __restrict__ agg, const float* __restrict__ stats,
                            const float* __restrict__ g, const float* __restrict__ be,
                            __half* __restrict__ buf, int n){
  int idx = blockIdx.x*blockDim.x + threadIdx.x;    // over n*16
  if(idx >= n*16) return;
  int c = (idx & 15)*4;
  float invn = 1.0f / n;
  float4 sm = *reinterpret_cast<const float4*>(stats + c);
  float4 sq = *reinterpret_cast<const float4*>(stats + 64 + c);
  float4 g4 = *reinterpret_cast<const float4*>(g + c);
  float4 b4 = *reinterpret_cast<const float4*>(be + c);
  float4 a  = reinterpret_cast<const float4*>(agg)[idx];
  __half2* bp = reinterpret_cast<__half2*>(buf) + idx*2;
  float2 ad01 = __half22float2(bp[0]);
  float2 ad23 = __half22float2(bp[1]);
  float o0,o1,o2,o3;
  { float m=sm.x*invn, v=sq.x*invn-m*m; o0 = fmaxf((a.x-m)*rsqrtf(v+BNEPS)*g4.x+b4.x,0.f)+ad01.x; }
  { float m=sm.y*invn, v=sq.y*invn-m*m; o1 = fmaxf((a.y-m)*rsqrtf(v+BNEPS)*g4.y+b4.y,0.f)+ad01.y; }
  { float m=sm.z*invn, v=sq.z*invn-m*m; o2 = fmaxf((a.z-m)*rsqrtf(v+BNEPS)*g4.z+b4.z,0.f)+ad23.x; }
  { float m=sm.w*invn, v=sq.w*invn-m*m; o3 = fmaxf((a.w-m)*rsqrtf(v+BNEPS)*g4.w+b4.w,0.f)+ad23.y; }
  bp[0] = __floats2half2_rn(o0,o1);
  bp[1] = __floats2half2_rn(o2,o3);
}

// block1 epilogue: bufA = half( relu(bn(agg)) + x@sW + sb ); folds 8 stats shards
__global__ void k_bn_sc4_h(const float* __restrict__ agg, const float* __restrict__ st1s,
                           const float* __restrict__ g, const float* __restrict__ be,
                           const float* __restrict__ X, const float* __restrict__ sW,
                           const float* __restrict__ sb, __half* __restrict__ out, int n){
  int idx = blockIdx.x*blockDim.x + threadIdx.x;    // over n*16
  if(idx >= n*16) return;
  int i = idx >> 4;
  int c = (idx & 15)*4;
  float invn = 1.0f / n;
  float4 xr = *reinterpret_cast<const float4*>(X + (size_t)i*4);
  float4 s0 = *reinterpret_cast<const float4*>(sW + c);
  float4 s1 = *reinterpret_cast<const float4*>(sW + 64 + c);
  float4 s2 = *reinterpret_cast<const float4*>(sW + 128 + c);
  float4 s3 = *reinterpret_cast<const float4*>(sW + 192 + c);
  float4 sb4 = *reinterpret_cast<const float4*>(sb + c);
  float4 sm = make_float4(0.f,0.f,0.f,0.f), sq = make_float4(0.f,0.f,0.f,0.f);
  #pragma unroll
  for(int sh = 0; sh < 8; sh++){
    float4 a4 = *reinterpret_cast<const float4*>(st1s + sh*128 + c);
    float4 b4 = *reinterpret_cast<const float4*>(st1s + sh*128 + 64 + c);
    sm.x += a4.x; sm.y += a4.y; sm.z += a4.z; sm.w += a4.w;
    sq.x += b4.x; sq.y += b4.y; sq.z += b4.z; sq.w += b4.w;
  }
  float4 g4 = *reinterpret_cast<const float4*>(g + c);
  float4 b4 = *reinterpret_cast<const float4*>(be + c);
  float4 a  = reinterpret_cast<const float4*>(agg)[idx];
  float o0,o1,o2,o3;
  #define BN1(X_, O_) { float sc = xr.x*s0.X_ + xr.y*s1.X_ + xr.z*s2.X_ + xr.w*s3.X_ + sb4.X_; \
    float m = sm.X_*invn; float v = sq.X_*invn - m*m; \
    O_ = fmaxf((a.X_-m)*rsqrtf(v+BNEPS)*g4.X_ + b4.X_, 0.f) + sc; }
  BN1(x,o0) BN1(y,o1) BN1(z,o2) BN1(w,o3)
  #undef BN1
  __half2* op = reinterpret_cast<__half2*>(out) + idx*2;
  op[0] = __floats2half2_rn(o0,o1);
  op[1] = __floats2half2_rn(o2,o3);
}

// ---------------- pooling / head ----------------

__global__ void k_pool(const float* __restrict__ H, const int* __restrict__ batch,
                       float* __restrict__ z, int n){
  int b = blockIdx.x, c = threadIdx.x;
  int lo = 0, hi = n;
  while(lo < hi){ int mid = (lo+hi)>>1; if(batch[mid] <  b) lo = mid+1; else hi = mid; }
  int start = lo;
  hi = n;
  while(lo < hi){ int mid = (lo+hi)>>1; if(batch[mid] <  b+1) lo = mid+1; else hi = mid; }
  int end = lo;
  float s = 0.f, mx = -INFINITY;
  for(int i = start; i < end; i++){
    float v = H[(size_t)i*128 + c];
    s += v; mx = fmaxf(mx, v);
  }
  int cnt = end - start;
  z[b*256 + c]       = s / fmaxf((float)cnt, 1.f);
  z[b*256 + 128 + c] = mx;
}

__global__ void k_head1(const float* __restrict__ z, const float* __restrict__ fW1,
                        const float* __restrict__ fb1, float* __restrict__ zr,
                        float* __restrict__ stats, int B){
  int idx = blockIdx.x*blockDim.x + threadIdx.x;
  int tid = threadIdx.x;
  float acc = 0.f;
  if(idx < B*128){
    int b = idx >> 7, c = idx & 127;
    acc = fb1[c];
    #pragma unroll 4
    for(int k = 0; k < 256; k++) acc = fmaf(z[b*256+k], fW1[k*128+c], acc);
    zr[idx] = acc;
  }
  __shared__ float rs[256], rs2[256];
  rs[tid] = acc; rs2[tid] = acc*acc;
  __syncthreads();
  if(tid < 128){
    atomicAdd(&stats[tid],     rs[tid]+rs[tid+128]);
    atomicAdd(&stats[128+tid], rs2[tid]+rs2[tid+128]);
  }
}

__global__ void k_final(const float* __restrict__ zr, const float* __restrict__ stats,
                        const float* __restrict__ fg, const float* __restrict__ fbe,
                        const float* __restrict__ fW2, const float* __restrict__ fb2,
                        float* __restrict__ out, int B){
  __shared__ float red[128];
  int b = blockIdx.x, c = threadIdx.x;
  float invn = 1.0f / B;
  float m  = stats[c]*invn;
  float v  = stats[128+c]*invn - m*m;
  float rs = rsqrtf(v + BNEPS);
  float val = fmaxf((zr[b*128+c]-m)*rs*fg[c] + fbe[c], 0.f) * fW2[c];
  red[c] = val;
  __syncthreads();
  for(int s = 64; s > 0; s >>= 1){
    if(c < s) red[c] += red[c+s];
    __syncthreads();
  }
  if(c == 0) out[b] = red[0] + fb2[0];
}

// ---------------- launch ----------------

extern "C" void kernel_launch(void* const* d_in, const int* in_sizes, int n_in,
                              void* d_out, int out_size, void* d_ws, size_t ws_size,
                              hipStream_t stream){
  const float* x   = (const float*)d_in[0];
  const int*   ei  = (const int*)  d_in[1];
  const float* ew  = (const float*)d_in[2];
  const int*   bat = (const int*)  d_in[3];
  const float* W1  = (const float*)d_in[4];  const float* b1  = (const float*)d_in[5];
  const float* g1  = (const float*)d_in[6];  const float* be1 = (const float*)d_in[7];
  const float* sW1 = (const float*)d_in[8];  const float* sb1 = (const float*)d_in[9];
  const float* W2  = (const float*)d_in[10]; const float* b2  = (const float*)d_in[11];
  const float* g2  = (const float*)d_in[12]; const float* be2 = (const float*)d_in[13];
  const float* W3  = (const float*)d_in[14]; const float* b3  = (const float*)d_in[15];
  const float* g3  = (const float*)d_in[16]; const float* be3 = (const float*)d_in[17];
  const float* sW3 = (const float*)d_in[18]; const float* sb3 = (const float*)d_in[19];
  const float* fW1 = (const float*)d_in[20]; const float* fb1 = (const float*)d_in[21];
  const float* fg  = (const float*)d_in[22]; const float* fbe = (const float*)d_in[23];
  const float* fW2 = (const float*)d_in[24]; const float* fb2 = (const float*)d_in[25];
  float* out = (float*)d_out;

  const int n = in_sizes[0] / 4;
  const int E = in_sizes[2];
  const int B = out_size;          // 512
  const int* src = ei;
  const int* dst = ei + E;

  auto GB = [](long long t){ return (int)((t + 255) / 256); };
  const int nscanb = (n + 255) / 256;   // <= 256 required for k_scan2
  const int ntiles = (n + 63) / 64;

  float* ws = (float*)d_ws;
  size_t off = 0;
  auto alloc = [&](size_t cnt)->float*{ float* p = ws + off; off += (cnt + 63) & ~size_t(63); return p; };

  const size_t npad = ((size_t)n + 63) & ~size_t(63);
  __half* bufA = (__half*)alloc((size_t)n * 32);   // n*64 halves
  float* hbuf  = alloc((size_t)n * 128);           // P buffers / block3 output
  float* agg   = alloc((size_t)n * 128);
  float* z     = alloc((size_t)B * 256);
  float* zr    = alloc((size_t)B * 128);
  float* zreg  = alloc(npad + 1024 + 768);         // cnt(n) + st1 shards(8x128) + st2/st3/stH
  int*   cnt   = (int*)zreg;
  float* st1s = zreg + npad;                       // 8 shards x (64 sum + 64 sumsq)
  float* st2  = st1s + 1024;
  float* st3  = st2 + 256;
  float* stH  = st3 + 256;
  float* dis    = alloc(n);
  int*   rowptr = (int*)alloc(n + 1);
  int*   bsum   = (int*)alloc(256);
  int*   rank   = (int*)alloc(E);
  int2*  erec   = (int2*)alloc((size_t)E * 2);

  // ---- CSR build: count records per-edge rank -> atomic-free scatter
  k_fill<<<GB(npad + 1024 + 768),256,0,stream>>>(zreg, (int)(npad + 1024 + 768), 0.f);
  k_count<<<GB(E),256,0,stream>>>(cnt, rank, dst, E);
  k_scan1<<<nscanb,256,0,stream>>>(cnt, rowptr, bsum, n);
  k_scan2<<<1,256,0,stream>>>(bsum, nscanb);
  k_scan3<<<GB(n),256,0,stream>>>(rowptr, bsum, n, E);
  k_scatter2<<<GB(E),256,0,stream>>>(src, dst, ew, rowptr, rank, erec, E);
  k_degdis<<<GB(n),256,0,stream>>>(erec, rowptr, dis, n);
  k_mknorm<<<GB(n),256,0,stream>>>(erec, rowptr, dis, n);

  // ---- block1: fused gather(x,4ch)+GEMM(4->64)+sharded stats -> agg; BN+ReLU+shortcut -> bufA(h)
  float* P = hbuf;
  k_gcn1_fused<<<2048,256,0,stream>>>(x, dis, rowptr, erec, W1, b1, agg, st1s, n);
  k_bn_sc4_h<<<GB((long long)n*16),256,0,stream>>>(agg, st1s, g1, be1, x, sW1, sb1, bufA, n);

  // ---- block2: P=gather(bufA h); agg=P@W2+b2 (+stats); BN+ReLU+identity -> bufA(h)
  k_gather64h<<<(n+3)/4,256,0,stream>>>(bufA, dis, rowptr, erec, P, n);
  k_gemm_tile<64><<<512,256,0,stream>>>(P, W2, b2, agg, st2, n, ntiles);
  k_bn_add4_h<<<GB((long long)n*16),256,0,stream>>>(agg, st2, g2, be2, bufA, n);

  // ---- block3: P=gather(bufA h); agg=P@W3+b3 (+stats); fused shortcut(h)+BN -> hbuf
  k_gather64h<<<(n+3)/4,256,0,stream>>>(bufA, dis, rowptr, erec, P, n);
  k_gemm_tile<128><<<512,256,0,stream>>>(P, W3, b3, agg, st3, n, ntiles);
  k_gemm_bnsc_tile_h<<<512,256,0,stream>>>(bufA, sW3, sb3, agg, st3, g3, be3, hbuf, n, ntiles);

  // ---- pooling + head ----
  k_pool<<<B,128,0,stream>>>(hbuf, bat, z, n);
  k_head1<<<GB((long long)B*128),256,0,stream>>>(z, fW1, fb1, zr, stH, B);
  k_final<<<B,128,0,stream>>>(zr, stH, fg, fbe, fW2, fb2, out, B);
}

// Round 16
// 419.067 us; speedup vs baseline: 1.1187x; 1.0254x over previous
//
#include <hip/hip_runtime.h>
#include <hip/hip_fp16.h>

#define BNEPS 1e-5f
#define DEGFIX 16777216.0f   // 2^24 fixed-point scale for packed weighted degree

// ---------------- utility ----------------

__global__ void k_fill(float* p, int n, float v){
  int i = blockIdx.x*blockDim.x + threadIdx.x;
  if(i < n) p[i] = v;
}

// ---------------- CSR build: packed 64-bit count+deg histogram ----------------
// One 64-bit atomicAdd per edge: bits [63:40] = edge count, [39:0] = fixed-point
// sum of weights (2^24 scale). rank = old>>40 -> scatter stays atomic-free.
// scan1 extracts count AND emits dis = rsqrt(1+deg); scatter computes the final
// norm inline (dis is L2-hot). Removes k_degdis + k_mknorm entirely.

__global__ void k_count64(unsigned long long* cnt64, int* rank,
                          const int* __restrict__ dst, const float* __restrict__ w, int E){
  int e = blockIdx.x*blockDim.x + threadIdx.x;
  if(e >= E) return;
  unsigned long long add = (1ull << 40) | (unsigned long long)(w[e] * DEGFIX);
  unsigned long long old = atomicAdd(&cnt64[dst[e]], add);
  rank[e] = (int)(old >> 40);
}

__global__ void k_scan1(const unsigned long long* __restrict__ cnt64, float* __restrict__ dis,
                        int* rowptr, int* bsum, int n){
  __shared__ int sh[256];
  int tid = threadIdx.x;
  int i = blockIdx.x*256 + tid;
  int v = 0;
  if(i < n){
    unsigned long long val = cnt64[i];
    v = (int)(val >> 40);
    float deg = (float)(val & ((1ull<<40)-1)) * (1.0f/DEGFIX);
    dis[i] = rsqrtf(1.0f + deg);        // self-loop weight 1
  }
  sh[tid] = v;
  __syncthreads();
  for(int o = 1; o < 256; o <<= 1){
    int t = (tid >= o) ? sh[tid-o] : 0;
    __syncthreads();
    sh[tid] += t;
    __syncthreads();
  }
  if(i < n) rowptr[i] = sh[tid] - v;
  if(tid == 255) bsum[blockIdx.x] = sh[255];
}

__global__ void k_scan2(int* bsum, int m){
  __shared__ int sh[256];
  int tid = threadIdx.x;
  int v = (tid < m) ? bsum[tid] : 0;
  sh[tid] = v;
  __syncthreads();
  for(int o = 1; o < 256; o <<= 1){
    int t = (tid >= o) ? sh[tid-o] : 0;
    __syncthreads();
    sh[tid] += t;
    __syncthreads();
  }
  if(tid < m) bsum[tid] = sh[tid] - v;
}

__global__ void k_scan3(int* rowptr, const int* bsum, int n, int E){
  int i = blockIdx.x*blockDim.x + threadIdx.x;
  if(i < n) rowptr[i] += bsum[i >> 8];
  if(i == 0) rowptr[n] = E;
}

// atomic-free scatter with inline norm: erec = {src, dis[src]*w*dis[dst]}
__global__ void k_scatter2(const int* __restrict__ src, const int* __restrict__ dst,
                           const float* __restrict__ w, const int* __restrict__ rowptr,
                           const int* __restrict__ rank, const float* __restrict__ dis,
                           int2* __restrict__ erec, int E){
  int e = blockIdx.x*blockDim.x + threadIdx.x;
  if(e >= E) return;
  int d = dst[e];
  int s = src[e];
  float nm = dis[s] * w[e] * dis[d];
  erec[rowptr[d] + rank[e]] = make_int2(s, __float_as_int(nm));
}

// ---------------- block1 fused: gather(x)[4ch] + GEMM(4->64) + SHARDED stats ----------------
// grid 2048 for latency hiding; stats sharded 8x so per-address atomic
// serialization is 256 not 2048 (R13/R14 lesson).

__global__ __launch_bounds__(256)
void k_gcn1_fused(const float* __restrict__ X, const float* __restrict__ dis,
                  const int* __restrict__ rowptr, const int2* __restrict__ erec,
                  const float* __restrict__ W, const float* __restrict__ bias,
                  float* __restrict__ H, float* __restrict__ st1s, int n){
  const int tid = threadIdx.x;
  const int lane = tid & 63;
  const int wid = tid >> 6;            // 4 waves/block
  const int eg = lane >> 2;            // 16 edge groups
  const int ch = lane & 3;             // input channel
  const float w0 = W[lane], w1 = W[64+lane], w2 = W[128+lane], w3 = W[192+lane];
  const float bc = bias[lane];
  float s = 0.f, s2 = 0.f;
  for(int i = blockIdx.x*4 + wid; i < n; i += gridDim.x*4){
    int e0 = rowptr[i], e1 = rowptr[i+1];
    float acc = 0.f;
    for(int j = e0 + eg; j < e1; j += 16){
      int2 r = erec[j];
      acc += X[(size_t)r.x*4 + ch] * __int_as_float(r.y);
    }
    if(eg == 0){
      float d = dis[i];
      acc += X[(size_t)i*4 + ch] * d * d;
    }
    acc += __shfl_xor(acc, 4);
    acc += __shfl_xor(acc, 8);
    acc += __shfl_xor(acc, 16);
    acc += __shfl_xor(acc, 32);
    float p0 = __shfl(acc, 0), p1 = __shfl(acc, 1);
    float p2 = __shfl(acc, 2), p3 = __shfl(acc, 3);
    float h = bc + p0*w0 + p1*w1 + p2*w2 + p3*w3;
    H[(size_t)i*64 + lane] = h;
    s += h; s2 += h*h;
  }
  __shared__ float rs[256], rs2[256];
  rs[tid] = s; rs2[tid] = s2;
  __syncthreads();
  if(tid < 64){
    float* stp = st1s + (blockIdx.x & 7)*128;
    atomicAdd(&stp[tid],    rs[tid]+rs[tid+64]+rs[tid+128]+rs[tid+192]);
    atomicAdd(&stp[64+tid], rs2[tid]+rs2[tid+64]+rs2[tid+128]+rs2[tid+192]);
  }
}

// ---------------- 64-channel gather from fp16 activations ----------------

__global__ void k_gather64h(const __half* __restrict__ H, const float* __restrict__ dis,
                            const int* __restrict__ rowptr, const int2* __restrict__ erec,
                            float* __restrict__ P, int n){
  int i = blockIdx.x*4 + threadIdx.x / 64;
  int c = threadIdx.x & 63;
  if(i >= n) return;
  float di = dis[i];
  float acc = __half2float(H[(size_t)i*64 + c])*di*di;
  int e0 = rowptr[i], e1 = rowptr[i+1];
  int j = e0;
  for(; j + 8 <= e1; j += 8){
    int2 r0 = erec[j],   r1 = erec[j+1], r2 = erec[j+2], r3 = erec[j+3];
    int2 r4 = erec[j+4], r5 = erec[j+5], r6 = erec[j+6], r7 = erec[j+7];
    float h0 = __half2float(H[(size_t)r0.x*64 + c]);
    float h1 = __half2float(H[(size_t)r1.x*64 + c]);
    float h2 = __half2float(H[(size_t)r2.x*64 + c]);
    float h3 = __half2float(H[(size_t)r3.x*64 + c]);
    float h4 = __half2float(H[(size_t)r4.x*64 + c]);
    float h5 = __half2float(H[(size_t)r5.x*64 + c]);
    float h6 = __half2float(H[(size_t)r6.x*64 + c]);
    float h7 = __half2float(H[(size_t)r7.x*64 + c]);
    acc += h0*__int_as_float(r0.y) + h1*__int_as_float(r1.y)
         + h2*__int_as_float(r2.y) + h3*__int_as_float(r3.y)
         + h4*__int_as_float(r4.y) + h5*__int_as_float(r5.y)
         + h6*__int_as_float(r6.y) + h7*__int_as_float(r7.y);
  }
  for(; j < e1; j++){
    int2 r = erec[j];
    acc += __half2float(H[(size_t)r.x*64 + c]) * __int_as_float(r.y);
  }
  P[(size_t)i*64 + c] = acc;
}

// ---------------- register-tiled LDS GEMMs (K=64) ----------------

template<int C>
__global__ __launch_bounds__(256)
void k_gemm_tile(const float* __restrict__ X, const float* __restrict__ W,
                 const float* __restrict__ bias, float* __restrict__ H,
                 float* __restrict__ stats, int n, int ntiles){
  const int RR = C/16;
  const int CG = C/4;
  __shared__ float Xs[64*65];
  __shared__ float Ws[64*C];
  __shared__ float sst[2*C];
  const int tid = threadIdx.x;
  const int cg = tid % CG, rg = tid / CG;
  const int c0 = cg*4;
  for(int t = tid; t < 16*C; t += 256)
    reinterpret_cast<float4*>(Ws)[t] = reinterpret_cast<const float4*>(W)[t];
  const float4 bc = *reinterpret_cast<const float4*>(bias + c0);
  float sacc[4] = {0,0,0,0}, qacc[4] = {0,0,0,0};
  const float4* X4 = reinterpret_cast<const float4*>(X);
  for(int tile = blockIdx.x; tile < ntiles; tile += gridDim.x){
    const int r0 = tile*64;
    __syncthreads();
    #pragma unroll
    for(int q = 0; q < 4; q++){
      int idx = tid + q*256;
      int row = idx >> 4, k4 = idx & 15;
      float4 v = (r0+row < n) ? X4[(size_t)(r0+row)*16 + k4] : make_float4(0.f,0.f,0.f,0.f);
      Xs[(4*k4+0)*65 + row] = v.x;
      Xs[(4*k4+1)*65 + row] = v.y;
      Xs[(4*k4+2)*65 + row] = v.z;
      Xs[(4*k4+3)*65 + row] = v.w;
    }
    __syncthreads();
    float acc[RR][4];
    #pragma unroll
    for(int r = 0; r < RR; r++){ acc[r][0]=bc.x; acc[r][1]=bc.y; acc[r][2]=bc.z; acc[r][3]=bc.w; }
    #pragma unroll 8
    for(int k = 0; k < 64; k++){
      float4 wv = reinterpret_cast<const float4*>(Ws)[k*CG + cg];
      #pragma unroll
      for(int r = 0; r < RR; r++){
        float xv = Xs[k*65 + rg*RR + r];
        acc[r][0] = fmaf(xv, wv.x, acc[r][0]);
        acc[r][1] = fmaf(xv, wv.y, acc[r][1]);
        acc[r][2] = fmaf(xv, wv.z, acc[r][2]);
        acc[r][3] = fmaf(xv, wv.w, acc[r][3]);
      }
    }
    #pragma unroll
    for(int r = 0; r < RR; r++){
      int row = r0 + rg*RR + r;
      if(row < n){
        *reinterpret_cast<float4*>(H + (size_t)row*C + c0) =
            make_float4(acc[r][0], acc[r][1], acc[r][2], acc[r][3]);
        #pragma unroll
        for(int j = 0; j < 4; j++){ sacc[j] += acc[r][j]; qacc[j] += acc[r][j]*acc[r][j]; }
      }
    }
  }
  for(int t = tid; t < 2*C; t += 256) sst[t] = 0.f;
  __syncthreads();
  #pragma unroll
  for(int j = 0; j < 4; j++){
    atomicAdd(&sst[c0+j], sacc[j]);
    atomicAdd(&sst[C+c0+j], qacc[j]);
  }
  __syncthreads();
  for(int t = tid; t < 2*C; t += 256) atomicAdd(&stats[t], sst[t]);
}

// out = relu(bn(agg)) + Xh@sW+sb  — shortcut GEMM from fp16 X + BN epilogue (C=128)
__global__ __launch_bounds__(256)
void k_gemm_bnsc_tile_h(const __half* __restrict__ Xh, const float* __restrict__ sW,
                        const float* __restrict__ sb,
                        const float* __restrict__ agg, const float* __restrict__ stats,
                        const float* __restrict__ g, const float* __restrict__ be,
                        float* __restrict__ out, int n, int ntiles){
  const int C = 128, RR = 8, CG = 32;
  __shared__ float Xs[64*65];
  __shared__ float Ws[64*C];
  const int tid = threadIdx.x;
  const int cg = tid % CG, rg = tid / CG;
  const int c0 = cg*4;
  for(int t = tid; t < 16*C; t += 256)
    reinterpret_cast<float4*>(Ws)[t] = reinterpret_cast<const float4*>(sW)[t];
  const float4 bc = *reinterpret_cast<const float4*>(sb + c0);
  float scal[4], shft[4];
  {
    float invn = 1.0f / n;
    #pragma unroll
    for(int j = 0; j < 4; j++){
      float m = stats[c0+j]*invn;
      float v = stats[C+c0+j]*invn - m*m;
      float rs = rsqrtf(v + BNEPS) * g[c0+j];
      scal[j] = rs;
      shft[j] = be[c0+j] - m*rs;
    }
  }
  for(int tile = blockIdx.x; tile < ntiles; tile += gridDim.x){
    const int r0 = tile*64;
    __syncthreads();
    #pragma unroll
    for(int q = 0; q < 2; q++){
      int t = tid + q*256;                 // 512 chunks of 8 halves
      int row = t >> 3, h8 = t & 7;
      float4 raw = make_float4(0.f,0.f,0.f,0.f);
      if(r0+row < n) raw = *reinterpret_cast<const float4*>(Xh + (size_t)(r0+row)*64 + h8*8);
      const __half2* hp = reinterpret_cast<const __half2*>(&raw);
      #pragma unroll
      for(int p = 0; p < 4; p++){
        float2 f = __half22float2(hp[p]);
        Xs[(h8*8 + 2*p    )*65 + row] = f.x;
        Xs[(h8*8 + 2*p + 1)*65 + row] = f.y;
      }
    }
    __syncthreads();
    float acc[RR][4];
    #pragma unroll
    for(int r = 0; r < RR; r++){ acc[r][0]=bc.x; acc[r][1]=bc.y; acc[r][2]=bc.z; acc[r][3]=bc.w; }
    #pragma unroll 8
    for(int k = 0; k < 64; k++){
      float4 wv = reinterpret_cast<const float4*>(Ws)[k*CG + cg];
      #pragma unroll
      for(int r = 0; r < RR; r++){
        float xv = Xs[k*65 + rg*RR + r];
        acc[r][0] = fmaf(xv, wv.x, acc[r][0]);
        acc[r][1] = fmaf(xv, wv.y, acc[r][1]);
        acc[r][2] = fmaf(xv, wv.z, acc[r][2]);
        acc[r][3] = fmaf(xv, wv.w, acc[r][3]);
      }
    }
    #pragma unroll
    for(int r = 0; r < RR; r++){
      int row = r0 + rg*RR + r;
      if(row < n){
        float4 a = *reinterpret_cast<const float4*>(agg + (size_t)row*C + c0);
        float4 o;
        o.x = fmaxf(a.x*scal[0] + shft[0], 0.f) + acc[r][0];
        o.y = fmaxf(a.y*scal[1] + shft[1], 0.f) + acc[r][1];
        o.z = fmaxf(a.z*scal[2] + shft[2], 0.f) + acc[r][2];
        o.w = fmaxf(a.w*scal[3] + shft[3], 0.f) + acc[r][3];
        *reinterpret_cast<float4*>(out + (size_t)row*C + c0) = o;
      }
    }
  }
}

// ---------------- BN applies (fp16 activation output) ----------------

// block2 epilogue: bufA = half( relu(bn(agg)) + bufA_old )   (C=64, in place)
__global__ void k_bn_add4_h(const float* __restrict__ agg, const float* __restrict__ stats,
                            const float* __restrict__ g, const float* __restrict__ be,
                            __half* __restrict__ buf, int n){
  int idx = blockIdx.x*blockDim.x + threadIdx.x;    // over n*16
  if(idx >= n*16) return;
  int c = (idx & 15)*4;
  float invn = 1.0f / n;
  float4 sm = *reinterpret_cast<const float4*>(stats + c);
  float4 sq = *reinterpret_cast<const float4*>(stats + 64 + c);
  float4 g4 = *reinterpret_cast<const float4*>(g + c);
  float4 b4 = *reinterpret_cast<const float4*>(be + c);
  float4 a  = reinterpret_cast<const float4*>(agg)[idx];
  __half2* bp = reinterpret_cast<__half2*>(buf) + idx*2;
  float2 ad01 = __half22float2(bp[0]);
  float2 ad23 = __half22float2(bp[1]);
  float o0,o1,o2,o3;
  { float m=sm.x*invn, v=sq.x*invn-m*m; o0 = fmaxf((a.x-m)*rsqrtf(v+BNEPS)*g4.x+b4.x,0.f)+ad01.x; }
  { float m=sm.y*invn, v=sq.y*invn-m*m; o1 = fmaxf((a.y-m)*rsqrtf(v+BNEPS)*g4.y+b4.y,0.f)+ad01.y; }
  { float m=sm.z*invn, v=sq.z*invn-m*m; o2 = fmaxf((a.z-m)*rsqrtf(v+BNEPS)*g4.z+b4.z,0.f)+ad23.x; }
  { float m=sm.w*invn, v=sq.w*invn-m*m; o3 = fmaxf((a.w-m)*rsqrtf(v+BNEPS)*g4.w+b4.w,0.f)+ad23.y; }
  bp[0] = __floats2half2_rn(o0,o1);
  bp[1] = __floats2half2_rn(o2,o3);
}

// block1 epilogue: bufA = half( relu(bn(agg)) + x@sW + sb ); folds 8 stats shards
__global__ void k_bn_sc4_h(const float* __restrict__ agg, const float* __restrict__ st1s,
                           const float* __restrict__ g, const float* __restrict__ be,
                           const float* __restrict__ X, const float* __restrict__ sW,
                           const float* __restrict__ sb, __half* __restrict__ out, int n){
  int idx = blockIdx.x*blockDim.x + threadIdx.x;    // over n*16
  if(idx >= n*16) return;
  int i = idx >> 4;
  int c = (idx & 15)*4;
  float invn = 1.0f / n;
  float4 xr = *reinterpret_cast<const float4*>(X + (size_t)i*4);
  float4 s0 = *reinterpret_cast<const float4*>(sW + c);
  float4 s1 = *reinterpret_cast<const float4*>(sW + 64 + c);
  float4 s2 = *reinterpret_cast<const float4*>(sW + 128 + c);
  float4 s3 = *reinterpret_cast<const float4*>(sW + 192 + c);
  float4 sb4 = *reinterpret_cast<const float4*>(sb + c);
  float4 sm = make_float4(0.f,0.f,0.f,0.f), sq = make_float4(0.f,0.f,0.f,0.f);
  #pragma unroll
  for(int sh = 0; sh < 8; sh++){
    float4 a4 = *reinterpret_cast<const float4*>(st1s + sh*128 + c);
    float4 b4 = *reinterpret_cast<const float4*>(st1s + sh*128 + 64 + c);
    sm.x += a4.x; sm.y += a4.y; sm.z += a4.z; sm.w += a4.w;
    sq.x += b4.x; sq.y += b4.y; sq.z += b4.z; sq.w += b4.w;
  }
  float4 g4 = *reinterpret_cast<const float4*>(g + c);
  float4 b4 = *reinterpret_cast<const float4*>(be + c);
  float4 a  = reinterpret_cast<const float4*>(agg)[idx];
  float o0,o1,o2,o3;
  #define BN1(X_, O_) { float sc = xr.x*s0.X_ + xr.y*s1.X_ + xr.z*s2.X_ + xr.w*s3.X_ + sb4.X_; \
    float m = sm.X_*invn; float v = sq.X_*invn - m*m; \
    O_ = fmaxf((a.X_-m)*rsqrtf(v+BNEPS)*g4.X_ + b4.X_, 0.f) + sc; }
  BN1(x,o0) BN1(y,o1) BN1(z,o2) BN1(w,o3)
  #undef BN1
  __half2* op = reinterpret_cast<__half2*>(out) + idx*2;
  op[0] = __floats2half2_rn(o0,o1);
  op[1] = __floats2half2_rn(o2,o3);
}

// ---------------- pooling / head ----------------

__global__ void k_pool(const float* __restrict__ H, const int* __restrict__ batch,
                       float* __restrict__ z, int n){
  int b = blockIdx.x, c = threadIdx.x;
  int lo = 0, hi = n;
  while(lo < hi){ int mid = (lo+hi)>>1; if(batch[mid] <  b) lo = mid+1; else hi = mid; }
  int start = lo;
  hi = n;
  while(lo < hi){ int mid = (lo+hi)>>1; if(batch[mid] <  b+1) lo = mid+1; else hi = mid; }
  int end = lo;
  float s = 0.f, mx = -INFINITY;
  for(int i = start; i < end; i++){
    float v = H[(size_t)i*128 + c];
    s += v; mx = fmaxf(mx, v);
  }
  int cnt = end - start;
  z[b*256 + c]       = s / fmaxf((float)cnt, 1.f);
  z[b*256 + 128 + c] = mx;
}

__global__ void k_head1(const float* __restrict__ z, const float* __restrict__ fW1,
                        const float* __restrict__ fb1, float* __restrict__ zr,
                        float* __restrict__ stats, int B){
  int idx = blockIdx.x*blockDim.x + threadIdx.x;
  int tid = threadIdx.x;
  float acc = 0.f;
  if(idx < B*128){
    int b = idx >> 7, c = idx & 127;
    acc = fb1[c];
    #pragma unroll 4
    for(int k = 0; k < 256; k++) acc = fmaf(z[b*256+k], fW1[k*128+c], acc);
    zr[idx] = acc;
  }
  __shared__ float rs[256], rs2[256];
  rs[tid] = acc; rs2[tid] = acc*acc;
  __syncthreads();
  if(tid < 128){
    atomicAdd(&stats[tid],     rs[tid]+rs[tid+128]);
    atomicAdd(&stats[128+tid], rs2[tid]+rs2[tid+128]);
  }
}

__global__ void k_final(const float* __restrict__ zr, const float* __restrict__ stats,
                        const float* __restrict__ fg, const float* __restrict__ fbe,
                        const float* __restrict__ fW2, const float* __restrict__ fb2,
                        float* __restrict__ out, int B){
  __shared__ float red[128];
  int b = blockIdx.x, c = threadIdx.x;
  float invn = 1.0f / B;
  float m  = stats[c]*invn;
  float v  = stats[128+c]*invn - m*m;
  float rs = rsqrtf(v + BNEPS);
  float val = fmaxf((zr[b*128+c]-m)*rs*fg[c] + fbe[c], 0.f) * fW2[c];
  red[c] = val;
  __syncthreads();
  for(int s = 64; s > 0; s >>= 1){
    if(c < s) red[c] += red[c+s];
    __syncthreads();
  }
  if(c == 0) out[b] = red[0] + fb2[0];
}

// ---------------- launch ----------------

extern "C" void kernel_launch(void* const* d_in, const int* in_sizes, int n_in,
                              void* d_out, int out_size, void* d_ws, size_t ws_size,
                              hipStream_t stream){
  const float* x   = (const float*)d_in[0];
  const int*   ei  = (const int*)  d_in[1];
  const float* ew  = (const float*)d_in[2];
  const int*   bat = (const int*)  d_in[3];
  const float* W1  = (const float*)d_in[4];  const float* b1  = (const float*)d_in[5];
  const float* g1  = (const float*)d_in[6];  const float* be1 = (const float*)d_in[7];
  const float* sW1 = (const float*)d_in[8];  const float* sb1 = (const float*)d_in[9];
  const float* W2  = (const float*)d_in[10]; const float* b2  = (const float*)d_in[11];
  const float* g2  = (const float*)d_in[12]; const float* be2 = (const float*)d_in[13];
  const float* W3  = (const float*)d_in[14]; const float* b3  = (const float*)d_in[15];
  const float* g3  = (const float*)d_in[16]; const float* be3 = (const float*)d_in[17];
  const float* sW3 = (const float*)d_in[18]; const float* sb3 = (const float*)d_in[19];
  const float* fW1 = (const float*)d_in[20]; const float* fb1 = (const float*)d_in[21];
  const float* fg  = (const float*)d_in[22]; const float* fbe = (const float*)d_in[23];
  const float* fW2 = (const float*)d_in[24]; const float* fb2 = (const float*)d_in[25];
  float* out = (float*)d_out;

  const int n = in_sizes[0] / 4;
  const int E = in_sizes[2];
  const int B = out_size;          // 512
  const int* src = ei;
  const int* dst = ei + E;

  auto GB = [](long long t){ return (int)((t + 255) / 256); };
  const int nscanb = (n + 255) / 256;   // <= 256 required for k_scan2
  const int ntiles = (n + 63) / 64;

  float* ws = (float*)d_ws;
  size_t off = 0;
  auto alloc = [&](size_t cnt)->float*{ float* p = ws + off; off += (cnt + 63) & ~size_t(63); return p; };

  const size_t npad = ((size_t)n + 63) & ~size_t(63);
  __half* bufA = (__half*)alloc((size_t)n * 32);   // n*64 halves
  float* hbuf  = alloc((size_t)n * 128);           // P buffers / block3 output
  float* agg   = alloc((size_t)n * 128);
  float* z     = alloc((size_t)B * 256);
  float* zr    = alloc((size_t)B * 128);
  float* zreg  = alloc(2*npad + 1024 + 768);       // cnt64(2*npad) + st1 shards + st2/st3/stH
  unsigned long long* cnt64 = (unsigned long long*)zreg;
  float* st1s = zreg + 2*npad;                     // 8 shards x (64 sum + 64 sumsq)
  float* st2  = st1s + 1024;
  float* st3  = st2 + 256;
  float* stH  = st3 + 256;
  float* dis    = alloc(n);
  int*   rowptr = (int*)alloc(n + 1);
  int*   bsum   = (int*)alloc(256);
  int*   rank   = (int*)alloc(E);
  int2*  erec   = (int2*)alloc((size_t)E * 2);

  // ---- CSR build: packed 64-bit count+deg -> rank, dis; inline norm at scatter
  k_fill<<<GB(2*npad + 1024 + 768),256,0,stream>>>(zreg, (int)(2*npad + 1024 + 768), 0.f);
  k_count64<<<GB(E),256,0,stream>>>(cnt64, rank, dst, ew, E);
  k_scan1<<<nscanb,256,0,stream>>>(cnt64, dis, rowptr, bsum, n);
  k_scan2<<<1,256,0,stream>>>(bsum, nscanb);
  k_scan3<<<GB(n),256,0,stream>>>(rowptr, bsum, n, E);
  k_scatter2<<<GB(E),256,0,stream>>>(src, dst, ew, rowptr, rank, dis, erec, E);

  // ---- block1: fused gather(x,4ch)+GEMM(4->64)+sharded stats -> agg; BN+ReLU+shortcut -> bufA(h)
  float* P = hbuf;
  k_gcn1_fused<<<2048,256,0,stream>>>(x, dis, rowptr, erec, W1, b1, agg, st1s, n);
  k_bn_sc4_h<<<GB((long long)n*16),256,0,stream>>>(agg, st1s, g1, be1, x, sW1, sb1, bufA, n);

  // ---- block2: P=gather(bufA h); agg=P@W2+b2 (+stats); BN+ReLU+identity -> bufA(h)
  k_gather64h<<<(n+3)/4,256,0,stream>>>(bufA, dis, rowptr, erec, P, n);
  k_gemm_tile<64><<<512,256,0,stream>>>(P, W2, b2, agg, st2, n, ntiles);
  k_bn_add4_h<<<GB((long long)n*16),256,0,stream>>>(agg, st2, g2, be2, bufA, n);

  // ---- block3: P=gather(bufA h); agg=P@W3+b3 (+stats); fused shortcut(h)+BN -> hbuf
  k_gather64h<<<(n+3)/4,256,0,stream>>>(bufA, dis, rowptr, erec, P, n);
  k_gemm_tile<128><<<512,256,0,stream>>>(P, W3, b3, agg, st3, n, ntiles);
  k_gemm_bnsc_tile_h<<<512,256,0,stream>>>(bufA, sW3, sb3, agg, st3, g3, be3, hbuf, n, ntiles);

  // ---- pooling + head ----
  k_pool<<<B,128,0,stream>>>(hbuf, bat, z, n);
  k_head1<<<GB((long long)B*128),256,0,stream>>>(z, fW1, fb1, zr, stH, B);
  k_final<<<B,128,0,stream>>>(zr, stH, fg, fbe, fW2, fb2, out, B);
}